// Round 14
// baseline (247.189 us; speedup 1.0000x reference)
//
#include <hip/hip_runtime.h>

// GCN: 2x (GCNConv + ReLU) + FC.  N=100000, E=1600000, F: 128 -> 64 -> 64 -> 32. fp32.
//
// R15: mm2/fc fused into agg kernels (row-local). aggmm block owns 64 nodes.
// R16-R18: aggmm gather restructures; 49 -> 42.7us.  Latency-bound: serial
//   per-node chunk round-trips are the exposed cost.
// R19-R22: binA range-reservation partition; best combo 226.8us.
// R23/R24: deg-atomic and LDS-histogram overlaps regressed; reverted.
// R25/R26: binA||mm1 role-split fusion + LDS slimming: 223.9us.
// R27: half-bucket sortB (2 blocks/bucket): 221.2us.  Partition pot is
//   diffuse (<4us/round); aggmm x2 = 87.5us = biggest visible item.
// R28: aggmm NODE-PAIR gather: wave splits into two 32-lane halves, each
//   owning one node of a pair (4 pairs/wave, was 8 serial nodes).  The two
//   halves' chunk loops run concurrently (divergence) -> exposed latency
//   windows ~ max(A,B) not A+B (~2x MLP).  Same 4 edges/gather-instruction
//   (2 per half); cross-half shfl_xor(32) reduce gone (4 shfl/node vs 8).
//   Tail uses wave-uniform remMax break + per-lane masking (avoids R21's
//   divergent-break codegen trap).  Phase 2 / all other kernels = R27.
// Pipeline (5): zeroK -> binmm(binA||mm1) -> sortB(halves,+H1 rescale) ->
//               aggmm(M=64,*dinv,bf16) -> aggmm(M=32,+bias,f32).

#define THREADS 256
#define THREADS_A 512
#define BIN_T 512
#define EPB 4096
#define BKT 256
#define CAP 8064
#define SORT_CAP 8192

typedef unsigned short ushort_t;
typedef __attribute__((ext_vector_type(8))) short short8;
typedef __attribute__((ext_vector_type(4))) float f32x4;
typedef __attribute__((ext_vector_type(2))) float f32x2;

__device__ __forceinline__ ushort_t f2bf(float f) {  // round-to-nearest-even
    unsigned u = __float_as_uint(f);
    u += 0x7FFFu + ((u >> 16) & 1u);
    return (ushort_t)(u >> 16);
}
__device__ __forceinline__ float bflo(unsigned v) { return __uint_as_float(v << 16); }
__device__ __forceinline__ float bfhi(unsigned v) { return __uint_as_float(v & 0xFFFF0000u); }

// ---- Kernel 0: zero the bucket counters (graph-capture-safe memset) --------

__global__ __launch_bounds__(BIN_T) void zeroK_kernel(int* __restrict__ p, int n) {
    const int i = (int)threadIdx.x;
    if (i < n) p[i] = 0;
}

// ---- Kernel 1: binmm - role-split binA (blocks<nblk) || mm1 (blocks>=nblk) -
// binA: bucket count + range reservation + coalesced scatter (30.8KB LDS,
//       wave-shfl scan).  mm1: 64-row MFMA tile, UNSCALED bf16 out, X staged
//       bf16 (34.8KB LDS).  Fused SMEM 34.8KB -> 4 blocks/CU.

template <int K, int M>
__global__ __launch_bounds__(THREADS_A) void binmm_kernel(const int* __restrict__ src,
                                                          const int* __restrict__ dst, int E,
                                                          int nb, int nblk,
                                                          int* __restrict__ cntg,
                                                          unsigned* __restrict__ stagePad,
                                                          const float* __restrict__ Xf,
                                                          const float* __restrict__ W,
                                                          ushort_t* __restrict__ Yv, int N) {
    constexpr int XROWU = K + 8;               // 136 ushorts
    constexpr int XB = 64 * XROWU * 2;         // 17408 B
    constexpr int WROW = K + 8;                // 136 ushorts
    constexpr int WB = M * WROW * 2;           // 17408 B -> mm1 = 34816 B
    constexpr int BA_ = EPB * 4 + EPB * 2 + BIN_T * 4 * 3 + 32;  // 30752 B
    constexpr int CB = 64 * M * 4;             // 16384 B (reuses smem[0..))
    constexpr int MM_ = XB + WB;
    constexpr int SMEM = (MM_ > BA_) ? ((MM_ > CB) ? MM_ : CB) : BA_;
    __shared__ __align__(16) char smem[SMEM];
    const int t = threadIdx.x;
    const int lane = t & 63, wid = t >> 6;

    if ((int)blockIdx.x < nblk) {
        // ---------------- binA path ----------------
        unsigned* ebuf2 = (unsigned*)smem;                 // 16384 B
        ushort_t* ebkt2 = (ushort_t*)(smem + EPB * 4);     //  8192 B
        int* cnt  = (int*)(smem + EPB * 4 + EPB * 2);      //  2048 B
        int* cur  = cnt + BIN_T;                           //  2048 B
        int* gb   = cur + BIN_T;                           //  2048 B
        int* wsum = gb + BIN_T;                            //    32 B
        const int e0 = blockIdx.x * EPB;
        const int n = min(EPB, E - e0);
        cnt[t] = 0;
        __syncthreads();
        for (int i = t; i < n; i += BIN_T)
            atomicAdd(&cnt[dst[e0 + i] >> 8], 1);
        __syncthreads();
        // Wave-shfl inclusive scan of cnt over 512 threads (2 barriers).
        const int v = cnt[t];
        int sv = v;
#pragma unroll
        for (int off = 1; off < 64; off <<= 1) {
            const int u = __shfl_up(sv, off, 64);
            if (lane >= off) sv += u;
        }
        if (lane == 63) wsum[wid] = sv;
        __syncthreads();
        int wbase = 0;
#pragma unroll
        for (int j = 0; j < 8; ++j) wbase += (j < wid) ? wsum[j] : 0;
        const int excl = sv + wbase - v;
        if (t < nb && v > 0) {
            const int resv = atomicAdd(&cntg[t], v);
            gb[t] = t * CAP + resv - excl;
        }
        cur[t] = excl;
        __syncthreads();
        // Reorder into bucket-sorted LDS (src/dst re-read, L2-hot).
        for (int i = t; i < n; i += BIN_T) {
            const int d = dst[e0 + i];
            const unsigned s = (unsigned)src[e0 + i];
            const int b = d >> 8;
            const int p = atomicAdd(&cur[b], 1);
            ebuf2[p] = ((unsigned)(d & (BKT - 1)) << 17) | s;
            ebkt2[p] = (ushort_t)b;
        }
        __syncthreads();
        // Coalesced-run output (address increments by 1 within a bucket run).
        for (int i = t; i < n; i += BIN_T)
            stagePad[gb[(int)ebkt2[i]] + i] = ebuf2[i];
        return;
    }

    // ---------------- mm1 path (unscaled; 8 waves; bf16-staged X) -----------
    const int row0 = ((int)blockIdx.x - nblk) * 64;
    ushort_t* XsU = (ushort_t*)smem;
    ushort_t* WsU = (ushort_t*)(smem + XB);
    for (int i = t; i < K * M; i += THREADS_A) {
        const int k = i / M, m = i % M;
        WsU[m * WROW + k] = f2bf(W[i]);
    }
    for (int i = t; i < 64 * K / 4; i += THREADS_A) {
        const int r = i / (K / 4), kc = i % (K / 4);
        const unsigned gr = (unsigned)min(row0 + r, N - 1);
        const float4 f = *(const float4*)(Xf + (size_t)gr * K + kc * 4);
        ushort4 pk = {f2bf(f.x), f2bf(f.y), f2bf(f.z), f2bf(f.w)};
        *(ushort4*)(XsU + (size_t)r * XROWU + kc * 4) = pk;
    }
    __syncthreads();

    const int w = wid;
    const int m0 = (w >> 1) * 16, lm = lane & 15, q = lane >> 4;
    const int c0 = (w & 1) * (M / 32);          // 2 col-tiles per wave (M=64)
    f32x4 acc[M / 32];
#pragma unroll
    for (int c = 0; c < M / 32; ++c) acc[c] = (f32x4)0.0f;

#pragma unroll
    for (int s = 0; s < K / 32; ++s) {
        const short8 a = *(const short8*)(XsU + (size_t)(m0 + lm) * XROWU + s * 32 + q * 8);
#pragma unroll
        for (int c = 0; c < M / 32; ++c) {
            const short8 b = *(const short8*)(WsU + (size_t)((c0 + c) * 16 + lm) * WROW + s * 32 + q * 8);
            acc[c] = __builtin_amdgcn_mfma_f32_16x16x32_bf16(a, b, acc[c], 0, 0, 0);
        }
    }
    __syncthreads();
    float* Cs = (float*)smem;                   // 16 KB, fits
#pragma unroll
    for (int c = 0; c < M / 32; ++c)
#pragma unroll
        for (int r = 0; r < 4; ++r)
            Cs[(size_t)(m0 + q * 4 + r) * M + (c0 + c) * 16 + lm] = acc[c][r];
    __syncthreads();

    for (int g = t; g < 64 * M / 4; g += THREADS_A) {
        const int r = g / (M / 4);
        const int gr = row0 + r;
        if (gr >= N) continue;
        const float4 o = *(const float4*)(Cs + (size_t)g * 4);
        const int col = (g % (M / 4)) * 4;
        ushort4 pk = {f2bf(o.x), f2bf(o.y), f2bf(o.z), f2bf(o.w)};
        *(ushort4*)(Yv + (size_t)gr * M + col) = pk;
    }
}

// ---- Kernel 2: half-bucket counting sort + row/dinv + H1 rescale -----------
// 2 blocks per bucket (782 total): both build the full-bucket histogram+scan
// (deterministic), each scatters + rescales only its 128-node half.

__global__ __launch_bounds__(THREADS) void sortB_kernel(const unsigned* __restrict__ stagePad,
                                                        const int* __restrict__ cntg,
                                                        int nb, int N,
                                                        int* __restrict__ row,
                                                        float* __restrict__ dinv,
                                                        unsigned* __restrict__ srt,
                                                        unsigned* __restrict__ H1) {
    __shared__ int cnt[BKT], cur[BKT];
    __shared__ float dv[BKT];
    __shared__ int wsum[4];
    const int blk = blockIdx.x;
    const int b = blk >> 1;                    // bucket
    const int h = blk & 1;                     // half (0: nodes 0-127, 1: 128-255)
    const int t = threadIdx.x;
    const int lane = t & 63, wid = t >> 6;
    // Bucket prefix: bs = sum(cntg[0..b-1]) via strided loads + shfl reduce.
    int part = 0;
    for (int j = t; j < b; j += THREADS) part += cntg[j];
#pragma unroll
    for (int off = 32; off > 0; off >>= 1) part += __shfl_xor(part, off, 64);
    if (lane == 0) wsum[wid] = part;
    cnt[t] = 0;
    __syncthreads();
    const int bs = wsum[0] + wsum[1] + wsum[2] + wsum[3];
    const int m = cntg[b];
    const unsigned* base = stagePad + (size_t)b * CAP;
    for (int i = t; i < m; i += THREADS)
        atomicAdd(&cnt[base[i] >> 17], 1);
    __syncthreads();
    // Wave-shfl inclusive scan over the 256 counts (identical in both halves).
    const int c = cnt[t];
    int sv = c;
#pragma unroll
    for (int off = 1; off < 64; off <<= 1) {
        const int u = __shfl_up(sv, off, 64);
        if (lane >= off) sv += u;
    }
    if (lane == 63) wsum[wid] = sv;
    __syncthreads();
    int wbase = 0;
#pragma unroll
    for (int j = 0; j < 4; ++j) wbase += (j < wid) ? wsum[j] : 0;
    const int excl = sv + wbase - c;
    cur[t] = excl;
    const float d = rsqrtf((float)c + 1.0f);
    dv[t] = d;
    const int node = b * BKT + t;
    if ((t >> 7) == h && node < N) {           // my half writes row/dinv
        row[node] = bs + excl;
        dinv[node] = d;
    }
    __syncthreads();
    // Scatter only my half's entries (disjoint srt ranges via shared scan).
    for (int i = t; i < m; i += THREADS) {
        const unsigned v = base[i];
        const int l = (int)(v >> 17);
        if ((l >> 7) == h) {
            const int pos = atomicAdd(&cur[l], 1);
            srt[bs + pos] = v & 0x1FFFFu;
        }
    }
    // H1 rescale for my half's 128 nodes (uint2-vectorized; L2-resident).
    const int node0 = b * BKT + (h << 7);
    const int nn = min(128, N - node0);
    if (nn > 0) {
        unsigned* Hrow = H1 + (unsigned)node0 * 32u;
        for (int i = t; i < nn * 16; i += THREADS) {
            const float di = dv[(h << 7) + (i >> 4)];
            uint2 v = *(uint2*)(Hrow + (size_t)i * 2);
            const float lo0 = bflo(v.x) * di, hi0 = bfhi(v.x) * di;
            const float lo1 = bflo(v.y) * di, hi1 = bfhi(v.y) * di;
            v.x = ((unsigned)f2bf(hi0) << 16) | (unsigned)f2bf(lo0);
            v.y = ((unsigned)f2bf(hi1) << 16) | (unsigned)f2bf(lo1);
            *(uint2*)(Hrow + (size_t)i * 2) = v;
        }
    }
}

// ---- Fused aggregate + row-local MFMA matmul (R28: node-pair gather) -------
// Block owns 64 nodes; 8 waves.  Wave w handles nodes w*8..w*8+7 as FOUR
// PAIRS: lane half (lane>>5) owns one node of the pair, 2 edge-slots of 16
// lanes each.  The two halves' chunk loops run concurrently (divergence) ->
// ~2x memory-level parallelism vs serial nodes.  relu(dinv*(Hself+sum)+abias)
// -> bf16 LDS tile Rl[64][72u].
// Phase 2 (MFMA):  Y[64][M] = Rl @ W; wave = (row-strip w>>1, col-half w&1).
// MODE 1: Y *= dinv -> bf16 pair table.  MODE 2: Y += fbias -> fp32 out.

template <int M, int MODE>
__global__ __launch_bounds__(THREADS_A) void aggmm_kernel(const unsigned* __restrict__ srt,
                                                          const int* __restrict__ row,
                                                          const float* __restrict__ dinv,
                                                          const unsigned* __restrict__ H2,
                                                          const float* __restrict__ abias,
                                                          const float* __restrict__ W,
                                                          const float* __restrict__ fbias,
                                                          void* __restrict__ Yv,
                                                          int N, int E) {
    constexpr int K = 64;
    constexpr int RROW = 36;                 // relu-tile row stride in dwords (72 ushorts)
    constexpr int RB = 64 * RROW * 4;        // 9216 B
    constexpr int WROW = K + 8;              // 72 ushorts
    constexpr int WB = M * WROW * 2;
    constexpr int CB = 64 * M * 4;
    constexpr int SMEM = (RB + WB > CB) ? (RB + WB) : CB;
    __shared__ __align__(16) char smem[SMEM];
    const int t = threadIdx.x;
    const int w = t >> 6, lane = t & 63;
    const int row0 = blockIdx.x * 64;

    // Stage W^T bf16 (phase 1 doesn't read it; barrier below covers it).
    ushort_t* WsU = (ushort_t*)(smem + RB);
    for (int i = t; i < K * M; i += THREADS_A) {
        const int k = i / M, m = i % M;
        WsU[m * WROW + k] = f2bf(W[i]);
    }

    // Phase 1: gather+relu, node-pair layout.
    unsigned* Rl = (unsigned*)smem;
    const int half = lane >> 5;              // which node of the pair
    const int hb = half << 5;                // half's base lane
    const int col2 = lane & 15;              // dword-pair within 32-dword row
    const int slotp = (lane >> 4) & 1;       // edge slot 0..1 within half
    const unsigned roff = (unsigned)(col2 * 2);
    const unsigned cap = (unsigned)(N - 1);
    const int node00 = row0 + w * 8;
    // Wave-invariant bias (hoisted off the per-node chain).
    const float4 bias4 = *(const float4*)(abias + col2 * 4);
    // Row/dinv prefetch: lanes 0..8 hold row[node00+lane] (E past the end).
    int rv;
    float dvv;
    {
        const int ridx = node00 + (int)lane;
        const bool okr = ridx < N;
        rv = okr ? row[ridx] : E;
        dvv = okr ? dinv[ridx] : 0.0f;
    }
    // Per-half start/end for pair 0 + cooperative chunk-0 idx prefetch.
    int myS = __shfl(rv, half, 64);
    int myE = __shfl(rv, half + 1, 64);
    unsigned idx0 = srt[myS + col2];
#pragma unroll 1
    for (int i = 0; i < 4; ++i) {
        const int nodeW = node00 + 2 * i;
        if (nodeW >= N) break;               // wave-uniform
        const int node = nodeW + half;       // per-lane (may be == N: guarded)
        const int start = myS, end = myE;
        unsigned idx = idx0;
        if (i < 3) {  // prefetch next pair's chunk-0 idx during this pair
            myS = __shfl(rv, 2 * (i + 1) + half, 64);
            myE = __shfl(rv, 2 * (i + 1) + half + 1, 64);
            idx0 = srt[myS + col2];
        }
        // Self-loop row, issued early (node==N reads pad -> discarded).
        const uint2 sv = *(const uint2*)(H2 + (((unsigned)node << 5) + roff));
        f32x2 a0 = {0.0f, 0.0f}, a1 = {0.0f, 0.0f};
        int base = start;
        // Divergent between halves: exposed latency ~ max(A,B) not A+B.
        while (base + 16 <= end) {
            unsigned idxn = 0;
            if (base + 16 < end)  // prefetch next chunk idx before the adds
                idxn = srt[base + 16 + col2];
#pragma unroll
            for (int g = 0; g < 8; ++g) {    // 8 groups x 2 edges per half
                const unsigned r = (unsigned)__shfl((int)idx, hb + g * 2 + slotp, 64);
                const uint2 v = *(const uint2*)(H2 + ((r << 5) + roff));
                a0 += (f32x2){bflo(v.x), bfhi(v.x)};
                a1 += (f32x2){bflo(v.y), bfhi(v.y)};
            }
            base += 16;
            idx = idxn;
        }
        const int rem = end - base;          // per-half 0..15
        const int remMax = max(rem, __shfl_xor(rem, 32, 64));  // wave-uniform
        if (remMax > 0) {
#pragma unroll
            for (int g = 0; g < 8; ++g) {
                if (g * 2 >= remMax) break;  // wave-uniform break
                const int e = g * 2 + slotp;
                unsigned r = (unsigned)__shfl((int)idx, hb + e, 64) & 0x1FFFFu;
                r = min(r, cap);             // garbage past end
                uint2 v = *(const uint2*)(H2 + ((r << 5) + roff));
                const bool ok = e < rem;
                v.x = ok ? v.x : 0u;
                v.y = ok ? v.y : 0u;
                a0 += (f32x2){bflo(v.x), bfhi(v.x)};
                a1 += (f32x2){bflo(v.y), bfhi(v.y)};
            }
        }
        // Reduce across the 2 edge-slots (lanes 16 apart within the half).
        a0.x += __shfl_xor(a0.x, 16, 64);
        a0.y += __shfl_xor(a0.y, 16, 64);
        a1.x += __shfl_xor(a1.x, 16, 64);
        a1.y += __shfl_xor(a1.y, 16, 64);
        const float d = __shfl(dvv, 2 * i + half, 64);
        if (slotp == 0 && node < N) {
            const float o0 = fmaxf(fmaf(a0.x + bflo(sv.x), d, bias4.x), 0.0f);
            const float o1 = fmaxf(fmaf(a0.y + bfhi(sv.x), d, bias4.y), 0.0f);
            const float o2 = fmaxf(fmaf(a1.x + bflo(sv.y), d, bias4.z), 0.0f);
            const float o3 = fmaxf(fmaf(a1.y + bfhi(sv.y), d, bias4.w), 0.0f);
            uint2 pk;
            pk.x = ((unsigned)f2bf(o1) << 16) | (unsigned)f2bf(o0);
            pk.y = ((unsigned)f2bf(o3) << 16) | (unsigned)f2bf(o2);
            *(uint2*)(Rl + (size_t)(w * 8 + 2 * i + half) * RROW + col2 * 2) = pk;
        }
    }
    __syncthreads();

    // Phase 2: MFMA over the relu tile. Wave = (row-strip, col-half).
    constexpr int TW = M / 32;               // col tiles per wave (64->2, 32->1)
    const int m0 = (w >> 1) * 16, lm = lane & 15, q = lane >> 4;
    const int c0 = (w & 1) * TW;
    f32x4 acc[TW];
#pragma unroll
    for (int c = 0; c < TW; ++c) acc[c] = (f32x4)0.0f;
#pragma unroll
    for (int s = 0; s < K / 32; ++s) {
        const short8 a = *(const short8*)((const ushort_t*)Rl + (size_t)(m0 + lm) * 72 + s * 32 + q * 8);
#pragma unroll
        for (int c = 0; c < TW; ++c) {
            const short8 b = *(const short8*)(WsU + (size_t)((c0 + c) * 16 + lm) * WROW + s * 32 + q * 8);
            acc[c] = __builtin_amdgcn_mfma_f32_16x16x32_bf16(a, b, acc[c], 0, 0, 0);
        }
    }
    __syncthreads();   // Rl/Ws dead; reuse as C [64][M] f32
    float* Cs = (float*)smem;
#pragma unroll
    for (int c = 0; c < TW; ++c)
#pragma unroll
        for (int r = 0; r < 4; ++r)
            Cs[(size_t)(m0 + q * 4 + r) * M + (c0 + c) * 16 + lm] = acc[c][r];
    __syncthreads();

    for (int g = t; g < 64 * M / 4; g += THREADS_A) {
        const int r = g / (M / 4);
        const int gr = row0 + r;
        if (gr >= N) continue;
        float4 o = *(const float4*)(Cs + (size_t)g * 4);
        const int col = (g % (M / 4)) * 4;
        if (MODE == 1) {
            const float d = dinv[gr];
            o.x *= d; o.y *= d; o.z *= d; o.w *= d;
            ushort4 pk = {f2bf(o.x), f2bf(o.y), f2bf(o.z), f2bf(o.w)};
            *(ushort4*)((ushort_t*)Yv + (size_t)gr * M + col) = pk;
        } else {
            o.x += fbias[col]; o.y += fbias[col + 1];
            o.z += fbias[col + 2]; o.w += fbias[col + 3];
            *(float4*)((float*)Yv + (size_t)gr * M + col) = o;
        }
    }
}

// ---- Launch ----------------------------------------------------------------

extern "C" void kernel_launch(void* const* d_in, const int* in_sizes, int n_in,
                              void* d_out, int out_size, void* d_ws, size_t ws_size,
                              hipStream_t stream) {
    const float* x   = (const float*)d_in[0];
    const int*   ei  = (const int*)d_in[1];   // [2, E] int32
    const float* W1  = (const float*)d_in[3];
    const float* b1  = (const float*)d_in[4];
    const float* W2  = (const float*)d_in[5];
    const float* b2  = (const float*)d_in[6];
    const float* Wfc = (const float*)d_in[7];
    const float* bfc = (const float*)d_in[8];
    float* out = (float*)d_out;

    const int N = in_sizes[0] / 128;
    const int E = in_sizes[1] / 2;
    const int* src = ei;
    const int* dst = ei + E;

    const int nb   = (N + BKT - 1) / BKT;     // 391 buckets
    const int nblk = (E + EPB - 1) / EPB;     // 391 edge-chunks

    // Workspace (256 B-aligned slices).
    char* p = (char*)d_ws;
    auto alloc = [&](size_t bytes) { char* r = p; p += (bytes + 255) & ~(size_t)255; return r; };
    int*      cntg   = (int*)alloc((size_t)nb * 4);
    unsigned* srt    = (unsigned*)alloc((size_t)E * 4);
    int*      row    = (int*)alloc((size_t)N * 4);     // also absorbs agg tail over-reads
    float*    dinv   = (float*)alloc((size_t)N * 4);
    ushort_t* bufH   = (ushort_t*)alloc((size_t)N * 64 * 2);   // H1 table (bf16)
    ushort_t* bufR   = (ushort_t*)alloc((size_t)N * 64 * 2);   // H2 table; doubles as stagePad
    unsigned* stagePad = (unsigned*)bufR;     // nb*CAP*4 = 12.61 MB <= 12.8 MB, dead before aggmm-1

    const int mmB = (N + 63) / 64;

    // 0) zero bucket counters (kernel, not hipMemsetAsync: graph-capture-safe).
    zeroK_kernel<<<1, BIN_T, 0, stream>>>(cntg, nb);
    // 1) fused: binA partition (blocks<nblk) || mm1 MFMA unscaled (blocks>=nblk).
    binmm_kernel<128, 64><<<nblk + mmB, THREADS_A, 0, stream>>>(
        src, dst, E, nb, nblk, cntg, stagePad, x, W1, bufH, N);
    // 2) half-bucket counting sort (2 blocks/bucket) -> srt, row, dinv; +H1 rescale.
    sortB_kernel<<<nb * 2, THREADS, 0, stream>>>(stagePad, cntg, nb, N, row, dinv, srt,
                                                 (unsigned*)bufH);
    // 3) agg layer1 + mm2 fused -> H2 table (bf16, *dinv).
    aggmm_kernel<64, 1><<<mmB, THREADS_A, 0, stream>>>(
        srt, row, dinv, (const unsigned*)bufH, b1, W2, nullptr, bufR, N, E);
    // 4) agg layer2 + fc fused -> fp32 out (+bfc).
    aggmm_kernel<32, 2><<<mmB, THREADS_A, 0, stream>>>(
        srt, row, dinv, (const unsigned*)bufR, b2, Wfc, bfc, out, N, E);
}